// Round 1
// baseline (204.025 us; speedup 1.0000x reference)
//
#include <hip/hip_runtime.h>

#define T_SEQ 4096
#define CDIM 384

typedef __attribute__((ext_vector_type(8))) short short8;
typedef __attribute__((ext_vector_type(4))) float float4e;

#define KSCALE 0.05103103630798288f            /* 384^-0.5 */
#define KE (KSCALE * 1.4426950408889634f)      /* scale * log2(e) */

__device__ inline unsigned short f2bf(float f) {
  unsigned u = __builtin_bit_cast(unsigned, f);
  u += 0x7FFFu + ((u >> 16) & 1u);             // round-to-nearest-even
  return (unsigned short)(u >> 16);
}

template<int C>
__device__ inline float dppf(float x) {
  return __builtin_bit_cast(float,
      __builtin_amdgcn_update_dpp(0, __builtin_bit_cast(int, x), C, 0xF, 0xF, false));
}
// reduce across the 16 lanes of a DPP row (all lanes get the result)
__device__ inline float rmax16(float x) {
  x = fmaxf(x, dppf<0xB1>(x));    // quad_perm(1,0,3,2)  xor1
  x = fmaxf(x, dppf<0x4E>(x));    // quad_perm(2,3,0,1)  xor2
  x = fmaxf(x, dppf<0x141>(x));   // row_half_mirror
  x = fmaxf(x, dppf<0x140>(x));   // row_mirror
  return x;
}
__device__ inline float rsum16(float x) {
  x += dppf<0xB1>(x);
  x += dppf<0x4E>(x);
  x += dppf<0x141>(x);
  x += dppf<0x140>(x);
  return x;
}

// ---------------- projection: K = x Wk^T + bk ; V(=Q) = x Wv^T + bv ----------
// grid 256 x 256 threads; each wave does a 16-row M-tile over all 128 cols.
__global__ __launch_bounds__(256) void proj_kernel(
    const float* __restrict__ x, const float* __restrict__ Wk, const float* __restrict__ bk,
    const float* __restrict__ Wv, const float* __restrict__ bv,
    unsigned short* __restrict__ Krow, unsigned short* __restrict__ Qrow,
    unsigned short* __restrict__ Vt) {
  const int tid = threadIdx.x;
  const int lane = tid & 63;
  const int wv = tid >> 6;
  const int lid = lane & 15, quad = lane >> 4;
  const int mtile = blockIdx.x * 4 + wv;
  const int row_a = mtile * 16 + lid;          // A-operand row for this lane
  const float* xr = x + (size_t)row_a * CDIM;

  float4e acc[8];
#pragma unroll
  for (int n = 0; n < 8; n++) acc[n] = (float4e){0.f, 0.f, 0.f, 0.f};

#pragma unroll
  for (int kc = 0; kc < 12; kc++) {
    const int ko = kc * 32 + quad * 8;
    float4e a0 = *(const float4e*)(xr + ko);
    float4e a1 = *(const float4e*)(xr + ko + 4);
    short8 af;
#pragma unroll
    for (int j = 0; j < 4; j++) { af[j] = (short)f2bf(a0[j]); af[4 + j] = (short)f2bf(a1[j]); }
#pragma unroll
    for (int n = 0; n < 8; n++) {
      const int col = n * 16 + lid;
      const float* wr = (n < 4) ? (Wk + (size_t)col * CDIM + ko)
                                : (Wv + (size_t)(col - 64) * CDIM + ko);
      float4e b0 = *(const float4e*)(wr);
      float4e b1 = *(const float4e*)(wr + 4);
      short8 bf;
#pragma unroll
      for (int j = 0; j < 4; j++) { bf[j] = (short)f2bf(b0[j]); bf[4 + j] = (short)f2bf(b1[j]); }
      acc[n] = __builtin_amdgcn_mfma_f32_16x16x32_bf16(af, bf, acc[n], 0, 0, 0);
    }
  }
  // epilogue: D rows = quad*4+i, cols = n*16+lid
  const int rbase = mtile * 16 + quad * 4;
#pragma unroll
  for (int n = 0; n < 8; n++) {
    const int col = n * 16 + lid;
    const float bias = (n < 4) ? bk[col] : bv[col - 64];
#pragma unroll
    for (int i = 0; i < 4; i++) {
      const int row = rbase + i;
      const unsigned short hv = f2bf(acc[n][i] + bias);
      if (n < 4) {
        Krow[(size_t)row * 64 + col] = hv;
      } else {
        const int hh = col - 64;
        Qrow[(size_t)row * 64 + hh] = hv;
        const int b = row >> 12, t = row & 4095;
        Vt[(size_t)(b * 64 + hh) * T_SEQ + t] = hv;
      }
    }
  }
}

// ---------------- flash attention, 1 wave per block, 32 q-rows/wave ----------
__global__ __launch_bounds__(64) void attn_kernel(
    const unsigned short* __restrict__ Krow, const unsigned short* __restrict__ Qrow,
    const unsigned short* __restrict__ Vt,
    float* __restrict__ Opart, float* __restrict__ MLpart,
    int seg_tiles, int maxseg) {
  const int bid = blockIdx.x;
  const int b = bid & 3;
  const int j = bid >> 2;
  int qt, seg;
  if (seg_tiles == 128) {          // unsplit fallback: heavy-first
    qt = 127 - j; seg = 0;
  } else {                          // split into 32-tile (1024-key) segments
    const int jr = 319 - j;         // heavy bands first
    if (jr < 32)       { qt = jr; seg = 0; }
    else if (jr < 96)  { const int t2 = jr - 32;  qt = 32 + (t2 >> 1); seg = t2 & 1; }
    else if (jr < 192) { const int t2 = jr - 96;  qt = 64 + t2 / 3;    seg = t2 % 3; }
    else               { const int t2 = jr - 192; qt = 96 + (t2 >> 2); seg = t2 & 3; }
  }
  const int q0 = qt * 32;
  const int lane = threadIdx.x;
  const int lid = lane & 15, quad = lane >> 4;
  const int t0 = seg * seg_tiles;
  const int tend0 = t0 + seg_tiles;
  const int t1 = (qt + 1 < tend0) ? (qt + 1) : tend0;

  const unsigned short* Qb = Qrow + (size_t)(b * T_SEQ + q0) * 64;
  const unsigned short* Kb = Krow + (size_t)(b * T_SEQ) * 64;
  const unsigned short* Vb = Vt + (size_t)(b * 64) * T_SEQ;

  short8 Qf[2][2];
#pragma unroll
  for (int r = 0; r < 2; r++)
#pragma unroll
    for (int h = 0; h < 2; h++)
      Qf[r][h] = *(const short8*)(Qb + (size_t)(r * 16 + lid) * 64 + h * 32 + quad * 8);

  float4e O[2][4];
  float4e mrow[2], lrow[2];
#pragma unroll
  for (int r = 0; r < 2; r++) {
#pragma unroll
    for (int cc = 0; cc < 4; cc++) O[r][cc] = (float4e){0.f, 0.f, 0.f, 0.f};
#pragma unroll
    for (int i = 0; i < 4; i++) { mrow[r][i] = -__builtin_inff(); lrow[r][i] = 0.f; }
  }

  __shared__ alignas(16) unsigned short Pb[2][16 * 40];  // stride 40 shorts = 80B
  const float4e zero4 = (float4e){0.f, 0.f, 0.f, 0.f};

  for (int kt = t0; kt < t1; kt++) {
    const int k0 = kt * 32;
    short8 Kf[2][2];
#pragma unroll
    for (int c = 0; c < 2; c++)
#pragma unroll
      for (int h = 0; h < 2; h++)
        Kf[c][h] = *(const short8*)(Kb + (size_t)(k0 + c * 16 + lid) * 64 + h * 32 + quad * 8);

    float4e S[2][2];
#pragma unroll
    for (int r = 0; r < 2; r++)
#pragma unroll
      for (int c = 0; c < 2; c++) {
        float4e s = __builtin_amdgcn_mfma_f32_16x16x32_bf16(Qf[r][0], Kf[c][0], zero4, 0, 0, 0);
        S[r][c] = __builtin_amdgcn_mfma_f32_16x16x32_bf16(Qf[r][1], Kf[c][1], s, 0, 0, 0);
      }

    short8 Vf[4];
#pragma unroll
    for (int cc = 0; cc < 4; cc++)
      Vf[cc] = *(const short8*)(Vb + (size_t)(cc * 16 + lid) * T_SEQ + k0 + quad * 8);

#pragma unroll
    for (int r = 0; r < 2; r++) {
      const int wbase = q0 + r * 16;
      if (k0 + 31 > wbase) {   // causal mask (diagonal tiles only)
#pragma unroll
        for (int c = 0; c < 2; c++) {
          const int colv = k0 + c * 16 + lid;
#pragma unroll
          for (int i = 0; i < 4; i++)
            if (colv > wbase + quad * 4 + i) S[r][c][i] = -__builtin_inff();
        }
      }
      float4e al, P0, P1;
#pragma unroll
      for (int i = 0; i < 4; i++) {
        const float tm = rmax16(fmaxf(S[r][0][i], S[r][1][i]));
        const float mn = fmaxf(mrow[r][i], tm);
        al[i] = __builtin_amdgcn_exp2f((mrow[r][i] - mn) * KE);
        const float mk = mn * KE;
        P0[i] = __builtin_amdgcn_exp2f(S[r][0][i] * KE - mk);
        P1[i] = __builtin_amdgcn_exp2f(S[r][1][i] * KE - mk);
        const float rs = rsum16(P0[i] + P1[i]);
        lrow[r][i] = lrow[r][i] * al[i] + rs;
        mrow[r][i] = mn;
        Pb[r][(quad * 4 + i) * 40 + lid]      = f2bf(P0[i]);
        Pb[r][(quad * 4 + i) * 40 + 16 + lid] = f2bf(P1[i]);
      }
#pragma unroll
      for (int cc = 0; cc < 4; cc++)
#pragma unroll
        for (int i = 0; i < 4; i++) O[r][cc][i] *= al[i];
    }
    __syncthreads();   // single-wave block: orders cross-lane LDS write->read
    const short8 Pf0 = *(const short8*)(&Pb[0][lid * 40 + quad * 8]);
    const short8 Pf1 = *(const short8*)(&Pb[1][lid * 40 + quad * 8]);
#pragma unroll
    for (int cc = 0; cc < 4; cc++) {
      O[0][cc] = __builtin_amdgcn_mfma_f32_16x16x32_bf16(Pf0, Vf[cc], O[0][cc], 0, 0, 0);
      O[1][cc] = __builtin_amdgcn_mfma_f32_16x16x32_bf16(Pf1, Vf[cc], O[1][cc], 0, 0, 0);
    }
    __syncthreads();   // WAR protection for next iteration's P writes
  }

  // write partial (unnormalized O, m, l)
  const size_t pidx = (size_t)(b * 128 + qt) * maxseg + seg;
  float* Ob = Opart + pidx * 2048;
#pragma unroll
  for (int r = 0; r < 2; r++)
#pragma unroll
    for (int cc = 0; cc < 4; cc++)
#pragma unroll
      for (int i = 0; i < 4; i++)
        Ob[(size_t)(r * 16 + quad * 4 + i) * 64 + cc * 16 + lid] = O[r][cc][i];
  float* ml = MLpart + pidx * 64;
  if (lid == 0) {
#pragma unroll
    for (int r = 0; r < 2; r++)
#pragma unroll
      for (int i = 0; i < 4; i++) {
        ml[r * 16 + quad * 4 + i]      = mrow[r][i];
        ml[32 + r * 16 + quad * 4 + i] = lrow[r][i];
      }
  }
}

// ---------------- combine split-K partials and normalize ---------------------
__global__ __launch_bounds__(256) void combine_kernel(
    const float* __restrict__ Opart, const float* __restrict__ MLpart,
    float* __restrict__ out, int seg_tiles, int maxseg) {
  const int bq = blockIdx.x;          // b*128 + qt
  const int qt = bq & 127;
  const int nseg = qt / seg_tiles + 1;
  const int tid = threadIdx.x;
  __shared__ float sW[4][32], sDen[32];
  const float* ml = MLpart + (size_t)bq * maxseg * 64;
  if (tid < 32) {
    float M = ml[tid];
    for (int s = 1; s < nseg; s++) M = fmaxf(M, ml[s * 64 + tid]);
    float den = 0.f;
    for (int s = 0; s < nseg; s++) {
      const float w = __builtin_amdgcn_exp2f((ml[s * 64 + tid] - M) * KE);
      sW[s][tid] = w;
      den += w * ml[s * 64 + 32 + tid];
    }
    sDen[tid] = den;
  }
  __syncthreads();
  const float* Ob = Opart + (size_t)bq * maxseg * 2048;
  float* ob = out + (size_t)bq * 2048;
#pragma unroll
  for (int e = tid; e < 2048; e += 256) {
    const int r = e >> 6;
    float acc = 0.f;
    for (int s = 0; s < nseg; s++) acc += sW[s][r] * Ob[s * 2048 + e];
    ob[e] = acc / sDen[r];
  }
}

extern "C" void kernel_launch(void* const* d_in, const int* in_sizes, int n_in,
                              void* d_out, int out_size, void* d_ws, size_t ws_size,
                              hipStream_t stream) {
  const float* x  = (const float*)d_in[0];
  const float* Wk = (const float*)d_in[1];
  const float* bk = (const float*)d_in[2];
  // d_in[3]=Wq, d_in[4]=bq are unused (reference bug: q uses value projection)
  const float* Wv = (const float*)d_in[5];
  const float* bv = (const float*)d_in[6];
  float* out = (float*)d_out;
  char* ws = (char*)d_ws;

  unsigned short* Krow = (unsigned short*)(ws);                   // 2 MB
  unsigned short* Qrow = (unsigned short*)(ws + (2u << 20));      // 2 MB
  unsigned short* Vt   = (unsigned short*)(ws + (4u << 20));      // 2 MB
  float* Opart = (float*)(ws + (6u << 20));

  const int split = (ws_size >= ((size_t)24 << 20)) ? 1 : 0;
  const int maxseg = split ? 4 : 1;
  const int seg_tiles = split ? 32 : 128;
  float* MLpart = (float*)(ws + (6u << 20) + (size_t)maxseg * 512 * 2048 * 4);

  hipLaunchKernelGGL(proj_kernel, dim3(256), dim3(256), 0, stream,
                     x, Wk, bk, Wv, bv, Krow, Qrow, Vt);
  const int nblk = split ? 1280 : 512;
  hipLaunchKernelGGL(attn_kernel, dim3(nblk), dim3(64), 0, stream,
                     Krow, Qrow, Vt, Opart, MLpart, seg_tiles, maxseg);
  hipLaunchKernelGGL(combine_kernel, dim3(512), dim3(256), 0, stream,
                     Opart, MLpart, out, seg_tiles, maxseg);
}

// Round 2
// 183.795 us; speedup vs baseline: 1.1101x; 1.1101x over previous
//
#include <hip/hip_runtime.h>

#define T_SEQ 4096
#define CDIM 384

typedef __attribute__((ext_vector_type(8))) short short8;
typedef __attribute__((ext_vector_type(4))) short short4e;
typedef __attribute__((ext_vector_type(4))) float float4e;

#define KSCALE 0.05103103630798288f            /* 384^-0.5 */
#define KE (KSCALE * 1.4426950408889634f)      /* scale * log2(e), folded into Q */

__device__ inline unsigned short f2bf(float f) {
  unsigned u = __builtin_bit_cast(unsigned, f);
  u += 0x7FFFu + ((u >> 16) & 1u);             // round-to-nearest-even
  return (unsigned short)(u >> 16);
}

template<int C>
__device__ inline float dppf(float x) {
  return __builtin_bit_cast(float,
      __builtin_amdgcn_update_dpp(0, __builtin_bit_cast(int, x), C, 0xF, 0xF, false));
}
__device__ inline float rmax16(float x) {
  x = fmaxf(x, dppf<0xB1>(x));    // quad_perm xor1
  x = fmaxf(x, dppf<0x4E>(x));    // quad_perm xor2
  x = fmaxf(x, dppf<0x141>(x));   // row_half_mirror
  x = fmaxf(x, dppf<0x140>(x));   // row_mirror
  return x;
}
__device__ inline float rsum16(float x) {
  x += dppf<0xB1>(x);
  x += dppf<0x4E>(x);
  x += dppf<0x141>(x);
  x += dppf<0x140>(x);
  return x;
}

// ---------------- projection: K = x Wk^T + bk ; V(=Q) = x Wv^T + bv ----------
// 256 blocks x 256 threads; block = 64 rows (4 waves x 16). W chunk staged in
// LDS as bf16 (stride 40 shorts to spread banks); Qrow stored pre-scaled by KE.
__global__ __launch_bounds__(256) void proj_kernel(
    const float* __restrict__ x, const float* __restrict__ Wk, const float* __restrict__ bk,
    const float* __restrict__ Wv, const float* __restrict__ bv,
    unsigned short* __restrict__ Krow, unsigned short* __restrict__ Qrow,
    unsigned short* __restrict__ Vt) {
  __shared__ alignas(16) unsigned short Wl[128 * 40];
  const int tid = threadIdx.x;
  const int lane = tid & 63;
  const int wv = tid >> 6;
  const int lid = lane & 15, quad = lane >> 4;
  const int rowbase = blockIdx.x * 64 + wv * 16;
  const float* xr = x + (size_t)(rowbase + lid) * CDIM;

  float4e acc[8];
#pragma unroll
  for (int n = 0; n < 8; n++) acc[n] = (float4e){0.f, 0.f, 0.f, 0.f};

  for (int kc = 0; kc < 12; kc++) {
    const int ko = kc * 32;
    // cooperative W chunk stage: 128 cols x 32 k (f32 -> bf16 LDS)
#pragma unroll
    for (int i = 0; i < 4; i++) {
      const int f = tid + 256 * i;          // 0..1023 float4-groups
      const int col = f >> 3, part = f & 7;
      const float* wsrc = (col < 64) ? (Wk + (size_t)col * CDIM + ko + part * 4)
                                     : (Wv + (size_t)(col - 64) * CDIM + ko + part * 4);
      float4e w4 = *(const float4e*)wsrc;
      short4e s;
#pragma unroll
      for (int j = 0; j < 4; j++) s[j] = (short)f2bf(w4[j]);
      *(short4e*)(&Wl[col * 40 + part * 4]) = s;
    }
    __syncthreads();
    float4e a0 = *(const float4e*)(xr + ko + quad * 8);
    float4e a1 = *(const float4e*)(xr + ko + quad * 8 + 4);
    short8 af;
#pragma unroll
    for (int j = 0; j < 4; j++) { af[j] = (short)f2bf(a0[j]); af[4 + j] = (short)f2bf(a1[j]); }
#pragma unroll
    for (int n = 0; n < 8; n++) {
      short8 bf = *(const short8*)(&Wl[(n * 16 + lid) * 40 + quad * 8]);
      acc[n] = __builtin_amdgcn_mfma_f32_16x16x32_bf16(af, bf, acc[n], 0, 0, 0);
    }
    __syncthreads();
  }
  // epilogue: D rows = quad*4+i, cols = n*16+lid
  const int rbase = rowbase + quad * 4;
#pragma unroll
  for (int n = 0; n < 8; n++) {
    const int col = n * 16 + lid;
    const float bias = (n < 4) ? bk[col] : bv[col - 64];
#pragma unroll
    for (int i = 0; i < 4; i++) {
      const int row = rbase + i;
      const float val = acc[n][i] + bias;
      if (n < 4) {
        Krow[(size_t)row * 64 + col] = f2bf(val);
      } else {
        const int hh = col - 64;
        Qrow[(size_t)row * 64 + hh] = f2bf(val * KE);   // pre-scaled query
        const int b = row >> 12, t = row & 4095;
        Vt[(size_t)(b * 64 + hh) * T_SEQ + t] = f2bf(val);
      }
    }
  }
}

// ---------------- flash attention, 1 wave / block, 32 q-rows, K/V prefetch ---
__global__ __launch_bounds__(64) void attn_kernel(
    const unsigned short* __restrict__ Krow, const unsigned short* __restrict__ Qrow,
    const unsigned short* __restrict__ Vt,
    float* __restrict__ Opart, float* __restrict__ MLpart,
    int seg_tiles, int maxseg, int segshift) {
  const int j = blockIdx.x;
  const int b = j & 3;
  const int rest = j >> 2;                   // heavy-first: qt descends
  const int qt = 127 - (rest >> segshift);
  const int seg = rest & (maxseg - 1);
  if (seg * seg_tiles > qt) return;          // segment entirely above diagonal

  const int q0 = qt * 32;
  const int lane = threadIdx.x;
  const int lid = lane & 15, quad = lane >> 4;
  const int t0 = seg * seg_tiles;
  const int tend0 = t0 + seg_tiles;
  const int t1 = (qt + 1 < tend0) ? (qt + 1) : tend0;

  const unsigned short* Qb = Qrow + (size_t)(b * T_SEQ + q0) * 64;
  const unsigned short* Kb = Krow + (size_t)(b * T_SEQ) * 64;
  const unsigned short* Vb = Vt + (size_t)(b * 64) * T_SEQ;

  short8 Qf[2][2];
#pragma unroll
  for (int r = 0; r < 2; r++)
#pragma unroll
    for (int h = 0; h < 2; h++)
      Qf[r][h] = *(const short8*)(Qb + (size_t)(r * 16 + lid) * 64 + h * 32 + quad * 8);

  float4e O[2][4];
  float4e mrow[2], lrow[2];
#pragma unroll
  for (int r = 0; r < 2; r++) {
#pragma unroll
    for (int cc = 0; cc < 4; cc++) O[r][cc] = (float4e){0.f, 0.f, 0.f, 0.f};
#pragma unroll
    for (int i = 0; i < 4; i++) { mrow[r][i] = -__builtin_inff(); lrow[r][i] = 0.f; }
  }

  __shared__ alignas(16) unsigned short Pb[2][16 * 40];
  const float4e zero4 = (float4e){0.f, 0.f, 0.f, 0.f};

  short8 Kc[2][2], Vc[4], Kn[2][2], Vn[4];
  {
    const int k0 = t0 * 32;
#pragma unroll
    for (int c = 0; c < 2; c++)
#pragma unroll
      for (int h = 0; h < 2; h++)
        Kc[c][h] = *(const short8*)(Kb + (size_t)(k0 + c * 16 + lid) * 64 + h * 32 + quad * 8);
#pragma unroll
    for (int cc = 0; cc < 4; cc++)
      Vc[cc] = *(const short8*)(Vb + (size_t)(cc * 16 + lid) * T_SEQ + k0 + quad * 8);
  }

  for (int kt = t0; kt < t1; kt++) {
    const int k0 = kt * 32;
    // ---- prefetch next tile (clamped reload of current on last iter) ----
    const int ktn = (kt + 1 < t1) ? kt + 1 : kt;
    const int kn0 = ktn * 32;
#pragma unroll
    for (int c = 0; c < 2; c++)
#pragma unroll
      for (int h = 0; h < 2; h++)
        Kn[c][h] = *(const short8*)(Kb + (size_t)(kn0 + c * 16 + lid) * 64 + h * 32 + quad * 8);
#pragma unroll
    for (int cc = 0; cc < 4; cc++)
      Vn[cc] = *(const short8*)(Vb + (size_t)(cc * 16 + lid) * T_SEQ + kn0 + quad * 8);

    // ---- S = Q K^T (Q pre-scaled, so S is in log2 domain) ----
    float4e S[2][2];
#pragma unroll
    for (int r = 0; r < 2; r++)
#pragma unroll
      for (int c = 0; c < 2; c++) {
        float4e s = __builtin_amdgcn_mfma_f32_16x16x32_bf16(Qf[r][0], Kc[c][0], zero4, 0, 0, 0);
        S[r][c] = __builtin_amdgcn_mfma_f32_16x16x32_bf16(Qf[r][1], Kc[c][1], s, 0, 0, 0);
      }

#pragma unroll
    for (int r = 0; r < 2; r++) {
      const int wbase = q0 + r * 16;
      if (k0 + 31 > wbase) {   // causal mask (diagonal tiles only)
#pragma unroll
        for (int c = 0; c < 2; c++) {
          const int colv = k0 + c * 16 + lid;
#pragma unroll
          for (int i = 0; i < 4; i++)
            if (colv > wbase + quad * 4 + i) S[r][c][i] = -__builtin_inff();
        }
      }
      float4e al, P0, P1;
#pragma unroll
      for (int i = 0; i < 4; i++) {
        const float tm = rmax16(fmaxf(S[r][0][i], S[r][1][i]));
        const float mn = fmaxf(mrow[r][i], tm);
        al[i] = __builtin_amdgcn_exp2f(mrow[r][i] - mn);
        P0[i] = __builtin_amdgcn_exp2f(S[r][0][i] - mn);
        P1[i] = __builtin_amdgcn_exp2f(S[r][1][i] - mn);
        const float rs = rsum16(P0[i] + P1[i]);
        lrow[r][i] = lrow[r][i] * al[i] + rs;
        mrow[r][i] = mn;
        Pb[r][(quad * 4 + i) * 40 + lid]      = f2bf(P0[i]);
        Pb[r][(quad * 4 + i) * 40 + 16 + lid] = f2bf(P1[i]);
      }
#pragma unroll
      for (int cc = 0; cc < 4; cc++)
#pragma unroll
        for (int i = 0; i < 4; i++) O[r][cc][i] *= al[i];
    }
    __syncthreads();
    const short8 Pf0 = *(const short8*)(&Pb[0][lid * 40 + quad * 8]);
    const short8 Pf1 = *(const short8*)(&Pb[1][lid * 40 + quad * 8]);
#pragma unroll
    for (int cc = 0; cc < 4; cc++) {
      O[0][cc] = __builtin_amdgcn_mfma_f32_16x16x32_bf16(Pf0, Vc[cc], O[0][cc], 0, 0, 0);
      O[1][cc] = __builtin_amdgcn_mfma_f32_16x16x32_bf16(Pf1, Vc[cc], O[1][cc], 0, 0, 0);
    }
    __syncthreads();   // WAR for next iteration's P writes
    // rotate prefetched registers
#pragma unroll
    for (int c = 0; c < 2; c++)
#pragma unroll
      for (int h = 0; h < 2; h++) Kc[c][h] = Kn[c][h];
#pragma unroll
    for (int cc = 0; cc < 4; cc++) Vc[cc] = Vn[cc];
  }

  // write partial (unnormalized O, m, l) — m/l in log2-scaled domain
  const size_t pidx = (size_t)(b * 128 + qt) * maxseg + seg;
  float* Ob = Opart + pidx * 2048;
#pragma unroll
  for (int r = 0; r < 2; r++)
#pragma unroll
    for (int cc = 0; cc < 4; cc++)
#pragma unroll
      for (int i = 0; i < 4; i++)
        Ob[(size_t)(r * 16 + quad * 4 + i) * 64 + cc * 16 + lid] = O[r][cc][i];
  float* ml = MLpart + pidx * 64;
  if (lid == 0) {
#pragma unroll
    for (int r = 0; r < 2; r++)
#pragma unroll
      for (int i = 0; i < 4; i++) {
        ml[r * 16 + quad * 4 + i]      = mrow[r][i];
        ml[32 + r * 16 + quad * 4 + i] = lrow[r][i];
      }
  }
}

// ---------------- combine split-K partials and normalize ---------------------
__global__ __launch_bounds__(256) void combine_kernel(
    const float* __restrict__ Opart, const float* __restrict__ MLpart,
    float* __restrict__ out, int segtileshift, int maxseg) {
  const int bq = blockIdx.x;          // b*128 + qt
  const int qt = bq & 127;
  const int nseg = (qt >> segtileshift) + 1;
  const int tid = threadIdx.x;
  __shared__ float sW[8][32], sDen[32];
  const float* ml = MLpart + (size_t)bq * maxseg * 64;
  if (tid < 32) {
    float M = ml[tid];
    for (int s = 1; s < nseg; s++) M = fmaxf(M, ml[s * 64 + tid]);
    float den = 0.f;
    for (int s = 0; s < nseg; s++) {
      const float w = __builtin_amdgcn_exp2f(ml[s * 64 + tid] - M);  // log2 domain
      sW[s][tid] = w;
      den += w * ml[s * 64 + 32 + tid];
    }
    sDen[tid] = den;
  }
  __syncthreads();
  const float* Ob = Opart + (size_t)bq * maxseg * 2048;
  float* ob = out + (size_t)bq * 2048;
#pragma unroll
  for (int e = tid; e < 2048; e += 256) {
    const int r = e >> 6;
    float acc = 0.f;
    for (int s = 0; s < nseg; s++) acc += sW[s][r] * Ob[s * 2048 + e];
    ob[e] = acc / sDen[r];
  }
}

extern "C" void kernel_launch(void* const* d_in, const int* in_sizes, int n_in,
                              void* d_out, int out_size, void* d_ws, size_t ws_size,
                              hipStream_t stream) {
  const float* x  = (const float*)d_in[0];
  const float* Wk = (const float*)d_in[1];
  const float* bk = (const float*)d_in[2];
  // d_in[3]=Wq, d_in[4]=bq unused (reference bug: q uses value projection)
  const float* Wv = (const float*)d_in[5];
  const float* bv = (const float*)d_in[6];
  float* out = (float*)d_out;
  char* ws = (char*)d_ws;

  unsigned short* Krow = (unsigned short*)(ws);                   // 2 MB
  unsigned short* Qrow = (unsigned short*)(ws + (2u << 20));      // 2 MB
  unsigned short* Vt   = (unsigned short*)(ws + (4u << 20));      // 2 MB
  float* Opart = (float*)(ws + (6u << 20));

  int maxseg, segshift, sts, seg_tiles;
  if (ws_size >= ((size_t)40 << 20))      { maxseg = 8; segshift = 3; sts = 4; seg_tiles = 16; }
  else if (ws_size >= ((size_t)24 << 20)) { maxseg = 4; segshift = 2; sts = 5; seg_tiles = 32; }
  else                                    { maxseg = 1; segshift = 0; sts = 7; seg_tiles = 128; }
  float* MLpart = (float*)(ws + (6u << 20) + (size_t)maxseg * 512 * 2048 * 4);

  hipLaunchKernelGGL(proj_kernel, dim3(256), dim3(256), 0, stream,
                     x, Wk, bk, Wv, bv, Krow, Qrow, Vt);
  hipLaunchKernelGGL(attn_kernel, dim3(4 * 128 * maxseg), dim3(64), 0, stream,
                     Krow, Qrow, Vt, Opart, MLpart, seg_tiles, maxseg, segshift);
  hipLaunchKernelGGL(combine_kernel, dim3(512), dim3(256), 0, stream,
                     Opart, MLpart, out, sts, maxseg);
}